// Round 2
// baseline (112.545 us; speedup 1.0000x reference)
//
#include <hip/hip_runtime.h>

// ApproxSiLU16 fixed-point: IN_FRAC=11, OUT_FRAC=10.
// seg LUT is exactly uniform: seg[i] = -16384 + i*1792 for i in [0,16].
// (linspace(-8,6,17)*2048 -> step 0.875*2048 = 1792, all integers exact)
#define MIN_SEG  (-16384)
#define MAX_SEG  (12288)
#define D_SEG    (1792)

typedef float f32x4 __attribute__((ext_vector_type(4)));

__device__ __forceinline__ float silu_one(float xf, const int* __restrict__ lut) {
    // round-half-even matches jnp.round
    int xi = __float2int_rn(xf * 2048.0f);
    int out_int;
    if (xi > MAX_SEG) {
        out_int = xi >> 1;                      // xi > 0 here, >> ok (IN_FRAC-OUT_FRAC=1)
    } else {
        int xc = max(xi, MIN_SEG);              // upper clamp implied by branch
        unsigned u = (unsigned)(xc - MIN_SEG);  // 0 .. 16*1792
        int idx = min((int)(u / D_SEG), 15);    // uniform-grid searchsorted (boundary-equiv)
        int dx  = (int)u - idx * D_SEG;         // 0 .. 1792
        int y0 = lut[idx];
        int y1 = lut[idx + 1];
        int t_fx = (int)((dx * 1024u + 896u) / 1792u);   // dx >= 0: C div == floor div
        out_int = y0 + ((t_fx * (y1 - y0) + 512) >> 10); // arith >> == Python floor shift
    }
    return (float)out_int * (1.0f / 1024.0f);
}

__global__ __launch_bounds__(256)
void approx_silu_fxp_nt_kernel(const float* __restrict__ x,
                               const int* __restrict__ silu_vals,
                               float* __restrict__ out,
                               int n4) {
    __shared__ int lut[17];
    if (threadIdx.x < 17) lut[threadIdx.x] = silu_vals[threadIdx.x];
    __syncthreads();

    const f32x4* __restrict__ xv = reinterpret_cast<const f32x4*>(x);
    f32x4* __restrict__ ov = reinterpret_cast<f32x4*>(out);

    const int stride = gridDim.x * blockDim.x;
    int i = blockIdx.x * blockDim.x + threadIdx.x;

    // Main loop: 4 independent float4 loads in flight per iteration (64 B/lane).
    for (; i + 3 * stride < n4; i += 4 * stride) {
        f32x4 v0 = __builtin_nontemporal_load(xv + i);
        f32x4 v1 = __builtin_nontemporal_load(xv + i + stride);
        f32x4 v2 = __builtin_nontemporal_load(xv + i + 2 * stride);
        f32x4 v3 = __builtin_nontemporal_load(xv + i + 3 * stride);

        f32x4 o0, o1, o2, o3;
        #pragma unroll
        for (int j = 0; j < 4; ++j) o0[j] = silu_one(v0[j], lut);
        #pragma unroll
        for (int j = 0; j < 4; ++j) o1[j] = silu_one(v1[j], lut);
        #pragma unroll
        for (int j = 0; j < 4; ++j) o2[j] = silu_one(v2[j], lut);
        #pragma unroll
        for (int j = 0; j < 4; ++j) o3[j] = silu_one(v3[j], lut);

        __builtin_nontemporal_store(o0, ov + i);
        __builtin_nontemporal_store(o1, ov + i + stride);
        __builtin_nontemporal_store(o2, ov + i + 2 * stride);
        __builtin_nontemporal_store(o3, ov + i + 3 * stride);
    }
    // Tail (not taken for the bench shape, kept for generality).
    for (; i < n4; i += stride) {
        f32x4 v = __builtin_nontemporal_load(xv + i);
        f32x4 o;
        #pragma unroll
        for (int j = 0; j < 4; ++j) o[j] = silu_one(v[j], lut);
        __builtin_nontemporal_store(o, ov + i);
    }
}

extern "C" void kernel_launch(void* const* d_in, const int* in_sizes, int n_in,
                              void* d_out, int out_size, void* d_ws, size_t ws_size,
                              hipStream_t stream) {
    const float* x = (const float*)d_in[0];
    // d_in[1] = seg (unused: uniform, derived in-kernel), d_in[2] = silu_vals
    const int* silu_vals = (const int*)d_in[2];
    float* out = (float*)d_out;

    int n = in_sizes[0];            // 67,108,864
    int n4 = n >> 2;                // float4 elements (n is a multiple of 4)

    int block = 256;
    int grid = 2048;                // 8 blocks/CU x 256 CUs; 4 f32x4/thread/iter
    approx_silu_fxp_nt_kernel<<<grid, block, 0, stream>>>(x, silu_vals, out, n4);
}

// Round 3
// 84.720 us; speedup vs baseline: 1.3284x; 1.3284x over previous
//
#include <hip/hip_runtime.h>

// ApproxSiLU16 fixed-point: IN_FRAC=11, OUT_FRAC=10.
// seg LUT is exactly uniform: seg[i] = -16384 + i*1792 for i in [0,16].
// (linspace(-8,6,17)*2048 -> step 0.875*2048 = 1792, all integers exact)
#define MIN_SEG  (-16384)
#define MAX_SEG  (12288)
#define D_SEG    (1792)

typedef float f32x4 __attribute__((ext_vector_type(4)));

__global__ __launch_bounds__(256)
void approx_silu_fxp_kernel(const float* __restrict__ x,
                            const int* __restrict__ silu_vals,
                            float* __restrict__ out,
                            int n4) {
    __shared__ int lut[17];
    if (threadIdx.x < 17) lut[threadIdx.x] = silu_vals[threadIdx.x];
    __syncthreads();

    const f32x4* __restrict__ x4 = reinterpret_cast<const f32x4*>(x);
    f32x4* __restrict__ o4 = reinterpret_cast<f32x4*>(out);

    int stride = gridDim.x * blockDim.x;
    for (int i = blockIdx.x * blockDim.x + threadIdx.x; i < n4; i += stride) {
        f32x4 v = x4[i];            // regular load: let L2 merge/alloc read lines
        f32x4 o;
        #pragma unroll
        for (int j = 0; j < 4; ++j) {
            // round-half-even matches jnp.round
            int xi = __float2int_rn(v[j] * 2048.0f);
            int out_int;
            if (xi > MAX_SEG) {
                // IN_FRAC - OUT_FRAC = 1 ; xi > 0 here so >> is fine
                out_int = xi >> 1;
            } else {
                int xc = max(xi, MIN_SEG);             // upper clamp implied by branch
                unsigned u = (unsigned)(xc - MIN_SEG); // 0 .. 16*1792
                int idx = min((int)(u / D_SEG), 15);   // uniform-grid searchsorted (boundary-equiv)
                int dx  = (int)u - idx * D_SEG;        // 0 .. 1792
                int y0 = lut[idx];
                int y1 = lut[idx + 1];
                int t_fx = (int)((dx * 1024u + 896u) / 1792u);   // dx >= 0: C div == floor div
                out_int = y0 + ((t_fx * (y1 - y0) + 512) >> 10); // arith >> == floor shift
            }
            o[j] = (float)out_int * (1.0f / 1024.0f);
        }
        // nt store ONLY: output is write-once/never-read — don't allocate in L2
        __builtin_nontemporal_store(o, o4 + i);
    }
}

extern "C" void kernel_launch(void* const* d_in, const int* in_sizes, int n_in,
                              void* d_out, int out_size, void* d_ws, size_t ws_size,
                              hipStream_t stream) {
    const float* x = (const float*)d_in[0];
    // d_in[1] = seg (unused: uniform, derived in-kernel), d_in[2] = silu_vals
    const int* silu_vals = (const int*)d_in[2];
    float* out = (float*)d_out;

    int n = in_sizes[0];            // 67,108,864
    int n4 = n >> 2;                // float4 elements (n is a multiple of 4)

    int block = 256;
    int grid = (n4 + block - 1) / block;
    if (grid > 2048) grid = 2048;   // 8 blocks/CU x 256 CUs = full 32-wave occupancy

    approx_silu_fxp_kernel<<<grid, block, 0, stream>>>(x, silu_vals, out, n4);
}